// Round 6
// baseline (329.408 us; speedup 1.0000x reference)
//
#include <hip/hip_runtime.h>
#include <math.h>

#define N_ATOMS  50000
#define N_NBRS   32
#define N_GAUSS  25
#define RCUT     5.0f
#define TT       4096      // nearest-neighbor filter table nodes
#define TROWS    32        // table rows per build block
#define MAXZ     100
#define PI_F     3.14159265358979323846f

typedef unsigned int   uint_t;
typedef unsigned short ushort_t;
typedef _Float16 f16;
typedef f16   f16x2 __attribute__((ext_vector_type(2)));
typedef f16   f16x4 __attribute__((ext_vector_type(4)));
typedef f16   f16x8 __attribute__((ext_vector_type(8)));
typedef float f32x4 __attribute__((ext_vector_type(4)));

// fast shifted softplus: max(x,0) + log(0.5 + 0.5*exp(-|x|))  (== softplus(x)-log2)
__device__ __forceinline__ float ssp(float x) {
  return fmaxf(x, 0.0f) + __logf(fmaf(0.5f, __expf(-fabsf(x)), 0.5f));
}
__device__ __forceinline__ f16x2 bch(uint_t u) {
  return __builtin_bit_cast(f16x2, u);
}
__device__ __forceinline__ uint_t hcb(f16x2 v) {
  return __builtin_bit_cast(uint_t, v);
}
// swizzled element offset into a [16][128] f16 LDS tile (8-elem chunk XOR row)
__device__ __forceinline__ int swz(int m, int e) {
  return m * 128 + ((((e >> 3) ^ m) & 15) << 3) + (e & 7);
}

// ---- prep 1: nearest table tabh[i][f] = f16( W(r_i)*fcut(r_i) ), r_i = i*RCUT/(TT-1)
// 128 blocks x 256 threads, 32 rows/block; fw2 + H staged in LDS; no spills.
__global__ void __launch_bounds__(256, 2)
build_table_kernel(const float* __restrict__ fw1,
                   const float* __restrict__ fb1,
                   const float* __restrict__ fw2,
                   const float* __restrict__ fb2,
                   f16* __restrict__ tabh,
                   float* __restrict__ out) {
  const int tid = threadIdx.x;
  const int i0  = blockIdx.x * TROWS;
  if (blockIdx.x == 0 && tid == 0) out[0] = 0.0f;  // re-zero accumulator every launch

  __shared__ float sW2[128 * 128];       // 64 KB, fw2 row-major [k][f]
  __shared__ float sH[TROWS][128];       // 16 KB, hidden activations

  // stage fw2
  #pragma unroll
  for (int t = 0; t < 16; ++t) {
    const int e = tid + t * 256;
    ((float4*)sW2)[e] = ((const float4*)fw2)[e];
  }

  // phase 1: H[row][f] = ssp(gauss(r_row) . fw1[:,f] + fb1[f])
  {
    const int f  = tid & 127;
    const int rh = (tid >> 7) * (TROWS / 2);
    const float delta = RCUT / (float)(N_GAUSS - 1);
    const float coeff = -0.5f / (delta * delta);
    const float b1v = fb1[f];
    for (int j = 0; j < TROWS / 2; ++j) {
      const float r = (float)(i0 + rh + j) * (RCUT / (float)(TT - 1));
      float h = b1v;
      #pragma unroll
      for (int g = 0; g < N_GAUSS; ++g) {
        const float d = r - (float)g * delta;
        h = fmaf(__expf(coeff * d * d), fw1[g * 128 + f], h);
      }
      sH[rh + j][f] = ssp(h);
    }
  }
  __syncthreads();

  // phase 2: tab[row][c] = H[row][:] @ fw2[:,c] + fb2[c], 4 rows x 4 cols per thread
  {
    const int c0 = (tid & 31) * 4;        // column quad
    const int rg = (tid >> 5) * 4;        // row group
    f32x4 acc[4];
    const float4 bv = *(const float4*)&fb2[c0];
    #pragma unroll
    for (int j = 0; j < 4; ++j) acc[j] = (f32x4){bv.x, bv.y, bv.z, bv.w};
    for (int k = 0; k < 128; ++k) {
      const float4 wv = *(const float4*)&sW2[k * 128 + c0];
      #pragma unroll
      for (int j = 0; j < 4; ++j) {
        const float hv = sH[rg + j][k];
        acc[j][0] = fmaf(hv, wv.x, acc[j][0]);
        acc[j][1] = fmaf(hv, wv.y, acc[j][1]);
        acc[j][2] = fmaf(hv, wv.z, acc[j][2]);
        acc[j][3] = fmaf(hv, wv.w, acc[j][3]);
      }
    }
    #pragma unroll
    for (int j = 0; j < 4; ++j) {
      const int i = i0 + rg + j;
      const float r = (float)i * (RCUT / (float)(TT - 1));
      const float fc = (r < RCUT) ? 0.5f * (__cosf(r * PI_F / RCUT) + 1.0f) : 0.0f;
      f16x4 o;
      #pragma unroll
      for (int c = 0; c < 4; ++c) o[c] = (f16)(acc[j][c] * fc);
      *(f16x4*)&tabh[i * 128 + c0] = o;
    }
  }
}

// ---- prep 2 (merged): weight transposes + ytab[z] = embed[z] @ in2f (100 rows)
__global__ void prep_merged_kernel(const float* __restrict__ w1,
                                   const float* __restrict__ w2,
                                   const float* __restrict__ mw1,
                                   const float* __restrict__ embed,
                                   const float* __restrict__ in2f,
                                   f16* __restrict__ w1ht,
                                   f16* __restrict__ w2ht,
                                   f16* __restrict__ mw1ht,
                                   f16* __restrict__ ytab) {
  const int c = blockIdx.x;    // output column / z index
  const int i = threadIdx.x;   // input row
  w1ht[c * 128 + i] = (f16)w1[i * 128 + c];
  w2ht[c * 128 + i] = (f16)w2[i * 128 + c];
  if (c < 64) mw1ht[c * 128 + i] = (f16)mw1[i * 64 + c];
  if (c < MAXZ) {              // uniform per block -> barrier is safe
    __shared__ float xs[128];
    xs[i] = embed[c * 128 + i];
    __syncthreads();
    float acc = 0.0f;
    for (int j = 0; j < 128; j += 4) {
      const float4 xv = *reinterpret_cast<const float4*>(&xs[j]);
      acc = fmaf(xv.x, in2f[(j + 0) * 128 + i], acc);
      acc = fmaf(xv.y, in2f[(j + 1) * 128 + i], acc);
      acc = fmaf(xv.z, in2f[(j + 2) * 128 + i], acc);
      acc = fmaf(xv.w, in2f[(j + 3) * 128 + i], acc);
    }
    ytab[c * 128 + i] = (f16)acc;
  }
}

// ---- main fused kernel: 256 threads, 16 atoms/block ----
__global__ void __launch_bounds__(256, 4)
schnet_main_kernel(const float* __restrict__ dR,
                   const int* __restrict__ Z,
                   const int* __restrict__ nbr,
                   const float* __restrict__ embed,
                   const f16* __restrict__ tabh,
                   const f16* __restrict__ ytab,
                   const f16* __restrict__ w1ht, const float* __restrict__ b1,
                   const f16* __restrict__ w2ht, const float* __restrict__ b2,
                   const f16* __restrict__ mw1ht, const float* __restrict__ mb1,
                   const float* __restrict__ mw2, const float* __restrict__ mb2,
                   float* __restrict__ out) {
  const int tid = threadIdx.x;
  const int wv  = tid >> 6;          // wave 0..3
  const int l   = tid & 63;
  const int a0  = blockIdx.x * 16;
  __shared__ int2  s_pk[16 * N_NBRS];   // 4 KB: {tab_row_byte, ytab_row_byte}
  __shared__ f16   sA[16 * 128];        // 4 KB swizzled activations
  __shared__ f16   sB[16 * 128];        // 4 KB swizzled activations
  __shared__ int   sZ[16];
  __shared__ float sRed[4];

  // -- stage per-pair row offsets (coalesced dR/nbr; Z gather L2-hit) --
  const float scale = (float)(TT - 1) / RCUT;
  #pragma unroll
  for (int t0 = 0; t0 < 2; ++t0) {
    const int t = tid + t0 * 256;
    const float r = dR[a0 * N_NBRS + t];
    const int  nb = nbr[a0 * N_NBRS + t];
    int i0 = (int)(r * scale + 0.5f);
    i0 = min(i0, TT - 1);
    const int z = Z[nb];
    s_pk[t] = make_int2(i0 << 8, z << 8);   // 256 B per row (128 x f16)
  }
  if (tid < 16) sZ[tid] = Z[a0 + tid];
  __syncthreads();

  // -- cfconv: wave owns atoms m0..m0+3; half-wave owns pair parity p;
  //    lane covers 4 channels (8 B) per load; 8-deep load pipeline --
  const int m0 = wv * 4;
  const int p  = l >> 5;          // 0: even k, 1: odd k
  const int cl = l & 31;
  const int choff = cl * 8;       // 4 ch * 2 B
  const char* tabc = (const char*)tabh;
  const char* ytc  = (const char*)ytab;

  f16x2 accX[4], accY[4];
  #pragma unroll
  for (int j = 0; j < 4; ++j) { accX[j] = (f16x2)0; accY[j] = (f16x2)0; }

  uint2 tw[8], yb[8];   // 8 slots in flight (16 loads/lane)

  // slot s in [0,64): atom j = s>>4, k-index kk = (s&15)*2 + p
#define CF_ISSUE(d, s) { \
    const int2 pk = s_pk[(m0 + ((s) >> 4)) * N_NBRS + (((s) & 15) * 2 + p)]; \
    tw[d] = *(const uint2*)(tabc + pk.x + choff); \
    yb[d] = *(const uint2*)(ytc  + pk.y + choff); }

#define CF_CONSUME(d, s) { \
    const int j = (s) >> 4; \
    accX[j] += bch(tw[d].x) * bch(yb[d].x); \
    accY[j] += bch(tw[d].y) * bch(yb[d].y); }

  #pragma unroll
  for (int d = 0; d < 8; ++d) CF_ISSUE(d, d)
  #pragma unroll
  for (int s = 0; s < 56; ++s) {
    CF_CONSUME(s & 7, s)
    CF_ISSUE(s & 7, s + 8)
  }
  #pragma unroll
  for (int s = 56; s < 64; ++s) CF_CONSUME(s & 7, s)
#undef CF_ISSUE
#undef CF_CONSUME

  // combine even/odd-k halves (bit-cast shuffle + packed add); lanes p==0 write
  #pragma unroll
  for (int j = 0; j < 4; ++j) {
    const uint_t ux = hcb(accX[j]);
    const uint_t uy = hcb(accY[j]);
    const uint_t ox = __shfl_xor(ux, 32, 64);
    const uint_t oy = __shfl_xor(uy, 32, 64);
    const f16x2 sx = bch(ux) + bch(ox);
    const f16x2 sy = bch(uy) + bch(oy);
    if (p == 0) {
      const int m = m0 + j;
      const int e = cl * 4;
      const int off = m * 128 + ((((e >> 3) ^ m) & 15) << 3) + (e & 7);
      uint2 pk;
      pk.x = hcb(sx);
      pk.y = hcb(sy);
      *(uint2*)&sA[off] = pk;
    }
  }
  __syncthreads();

  const int rc = l & 15;
  const int qk = l >> 4;
#define AFRAG(SRC, k0) (*(const f16x8*)&SRC[rc * 128 + (((((k0) >> 3) + qk) ^ rc) & 15) * 8])

  // -- f2out layer 1: h1 = ssp(agg @ w1 + b1); wave covers cols wv*32..+31 --
  f32x4 acc[2];
  #pragma unroll
  for (int t = 0; t < 2; ++t) {
    const float b = b1[wv * 32 + t * 16 + rc];
    acc[t] = (f32x4){b, b, b, b};
  }
  #pragma unroll
  for (int k0 = 0; k0 < 128; k0 += 32) {
    const f16x8 af = AFRAG(sA, k0);
    #pragma unroll
    for (int t = 0; t < 2; ++t) {
      const int c = wv * 32 + t * 16 + rc;
      const f16x8 bf = *(const f16x8*)&w1ht[c * 128 + k0 + qk * 8];
      acc[t] = __builtin_amdgcn_mfma_f32_16x16x32_f16(af, bf, acc[t], 0, 0, 0);
    }
  }
  #pragma unroll
  for (int t = 0; t < 2; ++t) {
    const int c = wv * 32 + t * 16 + rc;
    #pragma unroll
    for (int r = 0; r < 4; ++r) {
      sB[swz(qk * 4 + r, c)] = (f16)ssp(acc[t][r]);
    }
  }
  __syncthreads();

  // -- f2out layer 2 + residual: xnew = embed[Z] + (h1 @ w2 + b2) --
  #pragma unroll
  for (int t = 0; t < 2; ++t) {
    const float b = b2[wv * 32 + t * 16 + rc];
    acc[t] = (f32x4){b, b, b, b};
  }
  #pragma unroll
  for (int k0 = 0; k0 < 128; k0 += 32) {
    const f16x8 af = AFRAG(sB, k0);
    #pragma unroll
    for (int t = 0; t < 2; ++t) {
      const int c = wv * 32 + t * 16 + rc;
      const f16x8 bf = *(const f16x8*)&w2ht[c * 128 + k0 + qk * 8];
      acc[t] = __builtin_amdgcn_mfma_f32_16x16x32_f16(af, bf, acc[t], 0, 0, 0);
    }
  }
  __syncthreads();   // all sB reads done before sA overwrite below
  #pragma unroll
  for (int t = 0; t < 2; ++t) {
    const int c = wv * 32 + t * 16 + rc;
    #pragma unroll
    for (int r = 0; r < 4; ++r) {
      const int m = qk * 4 + r;
      const float x = embed[(size_t)sZ[m] * 128 + c] + acc[t][r];
      sA[swz(m, c)] = (f16)x;
    }
  }
  __syncthreads();

  // -- MLP layer 1: 128 -> 64; wave covers cols wv*16..+15 --
  const int c1 = wv * 16 + rc;
  const float bm = mb1[c1];
  f32x4 a2 = (f32x4){bm, bm, bm, bm};
  #pragma unroll
  for (int k0 = 0; k0 < 128; k0 += 32) {
    const f16x8 af = AFRAG(sA, k0);
    const f16x8 bf = *(const f16x8*)&mw1ht[c1 * 128 + k0 + qk * 8];
    a2 = __builtin_amdgcn_mfma_f32_16x16x32_f16(af, bf, a2, 0, 0, 0);
  }

  // -- MLP layer 2 (64 -> 1) + global sum --
  const float cm = mw2[c1];
  float v = 0.0f;
  #pragma unroll
  for (int r = 0; r < 4; ++r) v = fmaf(ssp(a2[r]), cm, v);
  #pragma unroll
  for (int o = 1; o < 64; o <<= 1) v += __shfl_xor(v, o, 64);
  if (l == 0) sRed[wv] = v;
  __syncthreads();
  if (tid == 0) {
    atomicAdd(out, 20.0f * (sRed[0] + sRed[1] + sRed[2] + sRed[3] + 16.0f * mb2[0]));
  }
#undef AFRAG
}

extern "C" void kernel_launch(void* const* d_in, const int* in_sizes, int n_in,
                              void* d_out, int out_size, void* d_ws, size_t ws_size,
                              hipStream_t stream) {
  const float* dR    = (const float*)d_in[0];
  const int*   Z     = (const int*)  d_in[1];
  const int*   nbr   = (const int*)  d_in[2];
  const float* embed = (const float*)d_in[3];
  const float* fw1   = (const float*)d_in[4];
  const float* fb1   = (const float*)d_in[5];
  const float* fw2   = (const float*)d_in[6];
  const float* fb2   = (const float*)d_in[7];
  const float* in2f  = (const float*)d_in[8];
  const float* w1    = (const float*)d_in[9];
  const float* b1    = (const float*)d_in[10];
  const float* w2    = (const float*)d_in[11];
  const float* b2    = (const float*)d_in[12];
  const float* mw1   = (const float*)d_in[13];
  const float* mb1   = (const float*)d_in[14];
  const float* mw2   = (const float*)d_in[15];
  const float* mb2   = (const float*)d_in[16];
  float* out = (float*)d_out;

  char* ws = (char*)d_ws;
  f16* tabh  = (f16*)ws;                                   // 1 MB
  f16* ytab  = (f16*)(ws + (size_t)1088 * 1024);           // 25.6 KB
  f16* w1ht  = (f16*)(ws + (size_t)1152 * 1024);           // 32 KB
  f16* w2ht  = (f16*)(ws + (size_t)1216 * 1024);           // 32 KB
  f16* mw1ht = (f16*)(ws + (size_t)1280 * 1024);           // 16 KB

  build_table_kernel<<<TT / TROWS, 256, 0, stream>>>(fw1, fb1, fw2, fb2, tabh, out);
  prep_merged_kernel<<<128, 128, 0, stream>>>(w1, w2, mw1, embed, in2f,
                                              w1ht, w2ht, mw1ht, ytab);
  schnet_main_kernel<<<N_ATOMS / 16, 256, 0, stream>>>(dR, Z, nbr, embed,
      tabh, ytab, w1ht, b1, w2ht, b2, mw1ht, mb1, mw2, mb2, out);
}

// Round 7
// 258.236 us; speedup vs baseline: 1.2756x; 1.2756x over previous
//
#include <hip/hip_runtime.h>
#include <math.h>

#define N_ATOMS  50000
#define N_NBRS   32
#define N_GAUSS  25
#define RCUT     5.0f
#define TT       4096      // nearest-neighbor filter table nodes
#define TROWS    32        // table rows per build block
#define MAXZ     100
#define PI_F     3.14159265358979323846f

typedef unsigned int   uint_t;
typedef unsigned short ushort_t;
typedef _Float16 f16;
typedef f16   f16x2 __attribute__((ext_vector_type(2)));
typedef f16   f16x4 __attribute__((ext_vector_type(4)));
typedef f16   f16x8 __attribute__((ext_vector_type(8)));
typedef float f32x4 __attribute__((ext_vector_type(4)));

// fast shifted softplus: max(x,0) + log(0.5 + 0.5*exp(-|x|))  (== softplus(x)-log2)
__device__ __forceinline__ float ssp(float x) {
  return fmaxf(x, 0.0f) + __logf(fmaf(0.5f, __expf(-fabsf(x)), 0.5f));
}
__device__ __forceinline__ f16x2 bch(uint_t u) {
  return __builtin_bit_cast(f16x2, u);
}
__device__ __forceinline__ uint_t hcb(f16x2 v) {
  return __builtin_bit_cast(uint_t, v);
}
// swizzled element offset into a [16][128] f16 LDS tile (8-elem chunk XOR row)
__device__ __forceinline__ int swz(int m, int e) {
  return m * 128 + ((((e >> 3) ^ m) & 15) << 3) + (e & 7);
}

// ---- prep 1: nearest table tabh[i][f] = f16( W(r_i)*fcut(r_i) ), r_i = i*RCUT/(TT-1)
__global__ void __launch_bounds__(256, 2)
build_table_kernel(const float* __restrict__ fw1,
                   const float* __restrict__ fb1,
                   const float* __restrict__ fw2,
                   const float* __restrict__ fb2,
                   f16* __restrict__ tabh,
                   float* __restrict__ out) {
  const int tid = threadIdx.x;
  const int i0  = blockIdx.x * TROWS;
  if (blockIdx.x == 0 && tid == 0) out[0] = 0.0f;  // re-zero accumulator every launch

  __shared__ float sW2[128 * 128];       // 64 KB, fw2 row-major [k][f]
  __shared__ float sH[TROWS][128];       // 16 KB, hidden activations

  #pragma unroll
  for (int t = 0; t < 16; ++t) {
    const int e = tid + t * 256;
    ((float4*)sW2)[e] = ((const float4*)fw2)[e];
  }

  // phase 1: H[row][f] = ssp(gauss(r_row) . fw1[:,f] + fb1[f])
  {
    const int f  = tid & 127;
    const int rh = (tid >> 7) * (TROWS / 2);
    const float delta = RCUT / (float)(N_GAUSS - 1);
    const float coeff = -0.5f / (delta * delta);
    const float b1v = fb1[f];
    for (int j = 0; j < TROWS / 2; ++j) {
      const float r = (float)(i0 + rh + j) * (RCUT / (float)(TT - 1));
      float h = b1v;
      #pragma unroll
      for (int g = 0; g < N_GAUSS; ++g) {
        const float d = r - (float)g * delta;
        h = fmaf(__expf(coeff * d * d), fw1[g * 128 + f], h);
      }
      sH[rh + j][f] = ssp(h);
    }
  }
  __syncthreads();

  // phase 2: tab[row][c] = H[row][:] @ fw2[:,c] + fb2[c]
  {
    const int c0 = (tid & 31) * 4;
    const int rg = (tid >> 5) * 4;
    f32x4 acc[4];
    const float4 bv = *(const float4*)&fb2[c0];
    #pragma unroll
    for (int j = 0; j < 4; ++j) acc[j] = (f32x4){bv.x, bv.y, bv.z, bv.w};
    for (int k = 0; k < 128; ++k) {
      const float4 wv = *(const float4*)&sW2[k * 128 + c0];
      #pragma unroll
      for (int j = 0; j < 4; ++j) {
        const float hv = sH[rg + j][k];
        acc[j][0] = fmaf(hv, wv.x, acc[j][0]);
        acc[j][1] = fmaf(hv, wv.y, acc[j][1]);
        acc[j][2] = fmaf(hv, wv.z, acc[j][2]);
        acc[j][3] = fmaf(hv, wv.w, acc[j][3]);
      }
    }
    #pragma unroll
    for (int j = 0; j < 4; ++j) {
      const int i = i0 + rg + j;
      const float r = (float)i * (RCUT / (float)(TT - 1));
      const float fc = (r < RCUT) ? 0.5f * (__cosf(r * PI_F / RCUT) + 1.0f) : 0.0f;
      f16x4 o;
      #pragma unroll
      for (int c = 0; c < 4; ++c) o[c] = (f16)(acc[j][c] * fc);
      *(f16x4*)&tabh[i * 128 + c0] = o;
    }
  }
}

// ---- prep 2 (merged): weight transposes + ytab[z] = embed[z] @ in2f (100 rows)
__global__ void prep_merged_kernel(const float* __restrict__ w1,
                                   const float* __restrict__ w2,
                                   const float* __restrict__ mw1,
                                   const float* __restrict__ embed,
                                   const float* __restrict__ in2f,
                                   f16* __restrict__ w1ht,
                                   f16* __restrict__ w2ht,
                                   f16* __restrict__ mw1ht,
                                   f16* __restrict__ ytab) {
  const int c = blockIdx.x;    // output column / z index
  const int i = threadIdx.x;   // input row
  w1ht[c * 128 + i] = (f16)w1[i * 128 + c];
  w2ht[c * 128 + i] = (f16)w2[i * 128 + c];
  if (c < 64) mw1ht[c * 128 + i] = (f16)mw1[i * 64 + c];
  if (c < MAXZ) {              // uniform per block -> barrier is safe
    __shared__ float xs[128];
    xs[i] = embed[c * 128 + i];
    __syncthreads();
    float acc = 0.0f;
    for (int j = 0; j < 128; j += 4) {
      const float4 xv = *reinterpret_cast<const float4*>(&xs[j]);
      acc = fmaf(xv.x, in2f[(j + 0) * 128 + i], acc);
      acc = fmaf(xv.y, in2f[(j + 1) * 128 + i], acc);
      acc = fmaf(xv.z, in2f[(j + 2) * 128 + i], acc);
      acc = fmaf(xv.w, in2f[(j + 3) * 128 + i], acc);
    }
    ytab[c * 128 + i] = (f16)acc;
  }
}

// ---- main fused kernel: 256 threads, 16 atoms/block ----
__global__ void __launch_bounds__(256, 3)
schnet_main_kernel(const float* __restrict__ dR,
                   const int* __restrict__ Z,
                   const int* __restrict__ nbr,
                   const float* __restrict__ embed,
                   const f16* __restrict__ tabh,
                   const f16* __restrict__ ytab,
                   const f16* __restrict__ w1ht, const float* __restrict__ b1,
                   const f16* __restrict__ w2ht, const float* __restrict__ b2,
                   const f16* __restrict__ mw1ht, const float* __restrict__ mb1,
                   const float* __restrict__ mw2, const float* __restrict__ mb2,
                   float* __restrict__ out) {
  const int tid = threadIdx.x;
  const int wv  = tid >> 6;          // wave 0..3
  const int l   = tid & 63;
  const int a0  = blockIdx.x * 16;
  __shared__ int2  s_pk[16 * N_NBRS];   // 4 KB: {tab_row_byte, ytab_row_byte}
  __shared__ f16   sA[16 * 128];        // 4 KB swizzled activations
  __shared__ f16   sB[16 * 128];        // 4 KB swizzled activations
  __shared__ int   sZ[16];
  __shared__ float sRed[4];

  // -- stage per-pair row offsets (coalesced dR/nbr; Z gather L2-hit) --
  const float scale = (float)(TT - 1) / RCUT;
  #pragma unroll
  for (int t0 = 0; t0 < 2; ++t0) {
    const int t = tid + t0 * 256;
    const float r = dR[a0 * N_NBRS + t];
    const int  nb = nbr[a0 * N_NBRS + t];
    int i0 = (int)(r * scale + 0.5f);
    i0 = min(i0, TT - 1);
    const int z = Z[nb];
    s_pk[t] = make_int2(i0 << 8, z << 8);   // 256 B per row (128 x f16)
  }
  if (tid < 16) sZ[tid] = Z[a0 + tid];
  __syncthreads();

  // -- cfconv: wave owns atoms m0..m0+3; half-wave owns pair parity p;
  //    lane covers 4 channels (8 B) per load.
  //    Two named banks x 8 slots; ALL loops trip-8, fully unrolled ->
  //    every array index compile-time constant (no scratch, rule #20). --
  const int m0 = wv * 4;
  const int p  = l >> 5;          // 0: even k, 1: odd k
  const int cl = l & 31;
  const int choff = cl * 8;       // 4 ch * 2 B
  const char* tabc = (const char*)tabh;
  const char* ytc  = (const char*)ytab;

  f16x2 accX[4], accY[4];
  #pragma unroll
  for (int j = 0; j < 4; ++j) { accX[j] = (f16x2)0; accY[j] = (f16x2)0; }

  uint2 twA[8], ybA[8], twB[8], ybB[8];

  // slot s in [0,64): atom j = s>>4, k-index kk = (s&15)*2 + p
#define IG(BANK, g) { \
    _Pragma("unroll") \
    for (int d = 0; d < 8; ++d) { \
      const int s = (g) * 8 + d; \
      const int2 pk = s_pk[(m0 + (s >> 4)) * N_NBRS + ((s & 15) * 2 + p)]; \
      tw##BANK[d] = *(const uint2*)(tabc + pk.x + choff); \
      yb##BANK[d] = *(const uint2*)(ytc  + pk.y + choff); \
    } }

#define CG(BANK, g) { \
    _Pragma("unroll") \
    for (int d = 0; d < 8; ++d) { \
      const int s = (g) * 8 + d; \
      const int j = s >> 4; \
      accX[j] += bch(tw##BANK[d].x) * bch(yb##BANK[d].x); \
      accY[j] += bch(tw##BANK[d].y) * bch(yb##BANK[d].y); \
    } }

  IG(A, 0) IG(B, 1)
  CG(A, 0) IG(A, 2)
  CG(B, 1) IG(B, 3)
  CG(A, 2) IG(A, 4)
  CG(B, 3) IG(B, 5)
  CG(A, 4) IG(A, 6)
  CG(B, 5) IG(B, 7)
  CG(A, 6)
  CG(B, 7)
#undef IG
#undef CG

  // combine even/odd-k halves (bit-cast shuffle + packed add); lanes p==0 write
  #pragma unroll
  for (int j = 0; j < 4; ++j) {
    const uint_t ux = hcb(accX[j]);
    const uint_t uy = hcb(accY[j]);
    const uint_t ox = __shfl_xor(ux, 32, 64);
    const uint_t oy = __shfl_xor(uy, 32, 64);
    const f16x2 sx = bch(ux) + bch(ox);
    const f16x2 sy = bch(uy) + bch(oy);
    if (p == 0) {
      const int m = m0 + j;
      const int e = cl * 4;
      const int off = m * 128 + ((((e >> 3) ^ m) & 15) << 3) + (e & 7);
      uint2 pk;
      pk.x = hcb(sx);
      pk.y = hcb(sy);
      *(uint2*)&sA[off] = pk;
    }
  }
  __syncthreads();

  const int rc = l & 15;
  const int qk = l >> 4;
#define AFRAG(SRC, k0) (*(const f16x8*)&SRC[rc * 128 + (((((k0) >> 3) + qk) ^ rc) & 15) * 8])

  // -- f2out layer 1: h1 = ssp(agg @ w1 + b1); wave covers cols wv*32..+31 --
  f32x4 acc[2];
  #pragma unroll
  for (int t = 0; t < 2; ++t) {
    const float b = b1[wv * 32 + t * 16 + rc];
    acc[t] = (f32x4){b, b, b, b};
  }
  #pragma unroll
  for (int k0 = 0; k0 < 128; k0 += 32) {
    const f16x8 af = AFRAG(sA, k0);
    #pragma unroll
    for (int t = 0; t < 2; ++t) {
      const int c = wv * 32 + t * 16 + rc;
      const f16x8 bf = *(const f16x8*)&w1ht[c * 128 + k0 + qk * 8];
      acc[t] = __builtin_amdgcn_mfma_f32_16x16x32_f16(af, bf, acc[t], 0, 0, 0);
    }
  }
  #pragma unroll
  for (int t = 0; t < 2; ++t) {
    const int c = wv * 32 + t * 16 + rc;
    #pragma unroll
    for (int r = 0; r < 4; ++r) {
      sB[swz(qk * 4 + r, c)] = (f16)ssp(acc[t][r]);
    }
  }
  __syncthreads();

  // -- f2out layer 2 + residual: xnew = embed[Z] + (h1 @ w2 + b2) --
  #pragma unroll
  for (int t = 0; t < 2; ++t) {
    const float b = b2[wv * 32 + t * 16 + rc];
    acc[t] = (f32x4){b, b, b, b};
  }
  #pragma unroll
  for (int k0 = 0; k0 < 128; k0 += 32) {
    const f16x8 af = AFRAG(sB, k0);
    #pragma unroll
    for (int t = 0; t < 2; ++t) {
      const int c = wv * 32 + t * 16 + rc;
      const f16x8 bf = *(const f16x8*)&w2ht[c * 128 + k0 + qk * 8];
      acc[t] = __builtin_amdgcn_mfma_f32_16x16x32_f16(af, bf, acc[t], 0, 0, 0);
    }
  }
  __syncthreads();   // all sB reads done before sA overwrite below
  #pragma unroll
  for (int t = 0; t < 2; ++t) {
    const int c = wv * 32 + t * 16 + rc;
    #pragma unroll
    for (int r = 0; r < 4; ++r) {
      const int m = qk * 4 + r;
      const float x = embed[(size_t)sZ[m] * 128 + c] + acc[t][r];
      sA[swz(m, c)] = (f16)x;
    }
  }
  __syncthreads();

  // -- MLP layer 1: 128 -> 64; wave covers cols wv*16..+15 --
  const int c1 = wv * 16 + rc;
  const float bm = mb1[c1];
  f32x4 a2 = (f32x4){bm, bm, bm, bm};
  #pragma unroll
  for (int k0 = 0; k0 < 128; k0 += 32) {
    const f16x8 af = AFRAG(sA, k0);
    const f16x8 bf = *(const f16x8*)&mw1ht[c1 * 128 + k0 + qk * 8];
    a2 = __builtin_amdgcn_mfma_f32_16x16x32_f16(af, bf, a2, 0, 0, 0);
  }

  // -- MLP layer 2 (64 -> 1) + global sum --
  const float cm = mw2[c1];
  float v = 0.0f;
  #pragma unroll
  for (int r = 0; r < 4; ++r) v = fmaf(ssp(a2[r]), cm, v);
  #pragma unroll
  for (int o = 1; o < 64; o <<= 1) v += __shfl_xor(v, o, 64);
  if (l == 0) sRed[wv] = v;
  __syncthreads();
  if (tid == 0) {
    atomicAdd(out, 20.0f * (sRed[0] + sRed[1] + sRed[2] + sRed[3] + 16.0f * mb2[0]));
  }
#undef AFRAG
}

extern "C" void kernel_launch(void* const* d_in, const int* in_sizes, int n_in,
                              void* d_out, int out_size, void* d_ws, size_t ws_size,
                              hipStream_t stream) {
  const float* dR    = (const float*)d_in[0];
  const int*   Z     = (const int*)  d_in[1];
  const int*   nbr   = (const int*)  d_in[2];
  const float* embed = (const float*)d_in[3];
  const float* fw1   = (const float*)d_in[4];
  const float* fb1   = (const float*)d_in[5];
  const float* fw2   = (const float*)d_in[6];
  const float* fb2   = (const float*)d_in[7];
  const float* in2f  = (const float*)d_in[8];
  const float* w1    = (const float*)d_in[9];
  const float* b1    = (const float*)d_in[10];
  const float* w2    = (const float*)d_in[11];
  const float* b2    = (const float*)d_in[12];
  const float* mw1   = (const float*)d_in[13];
  const float* mb1   = (const float*)d_in[14];
  const float* mw2   = (const float*)d_in[15];
  const float* mb2   = (const float*)d_in[16];
  float* out = (float*)d_out;

  char* ws = (char*)d_ws;
  f16* tabh  = (f16*)ws;                                   // 1 MB
  f16* ytab  = (f16*)(ws + (size_t)1088 * 1024);           // 25.6 KB
  f16* w1ht  = (f16*)(ws + (size_t)1152 * 1024);           // 32 KB
  f16* w2ht  = (f16*)(ws + (size_t)1216 * 1024);           // 32 KB
  f16* mw1ht = (f16*)(ws + (size_t)1280 * 1024);           // 16 KB

  build_table_kernel<<<TT / TROWS, 256, 0, stream>>>(fw1, fb1, fw2, fb2, tabh, out);
  prep_merged_kernel<<<128, 128, 0, stream>>>(w1, w2, mw1, embed, in2f,
                                              w1ht, w2ht, mw1ht, ytab);
  schnet_main_kernel<<<N_ATOMS / 16, 256, 0, stream>>>(dR, Z, nbr, embed,
      tabh, ytab, w1ht, b1, w2ht, b2, mw1ht, mb1, mw2, mb2, out);
}

// Round 8
// 82.778 us; speedup vs baseline: 3.9794x; 3.1196x over previous
//
#include <hip/hip_runtime.h>
#include <math.h>

#define N_ATOMS  50000
#define N_NBRS   32
#define N_GAUSS  25
#define RCUT     5.0f
#define TT       4096      // nearest-neighbor filter table nodes
#define TROWS    32        // table rows per build block
#define MAXZ     100
#define PI_F     3.14159265358979323846f

typedef unsigned int   uint_t;
typedef unsigned short ushort_t;
typedef _Float16 f16;
typedef f16   f16x2 __attribute__((ext_vector_type(2)));
typedef f16   f16x4 __attribute__((ext_vector_type(4)));
typedef f16   f16x8 __attribute__((ext_vector_type(8)));
typedef float f32x4 __attribute__((ext_vector_type(4)));

// fast shifted softplus: max(x,0) + log(0.5 + 0.5*exp(-|x|))  (== softplus(x)-log2)
__device__ __forceinline__ float ssp(float x) {
  return fmaxf(x, 0.0f) + __logf(fmaf(0.5f, __expf(-fabsf(x)), 0.5f));
}
__device__ __forceinline__ f16x2 bch(uint_t u) {
  return __builtin_bit_cast(f16x2, u);
}
__device__ __forceinline__ uint_t hcb(f16x2 v) {
  return __builtin_bit_cast(uint_t, v);
}
// swizzled element offset into a [16][128] f16 LDS tile (8-elem chunk XOR row)
__device__ __forceinline__ int swz(int m, int e) {
  return m * 128 + ((((e >> 3) ^ m) & 15) << 3) + (e & 7);
}

// ---- prep 1: nearest table tabh[i][f] = f16( W(r_i)*fcut(r_i) ), r_i = i*RCUT/(TT-1)
__global__ void __launch_bounds__(256, 2)
build_table_kernel(const float* __restrict__ fw1,
                   const float* __restrict__ fb1,
                   const float* __restrict__ fw2,
                   const float* __restrict__ fb2,
                   f16* __restrict__ tabh,
                   float* __restrict__ out) {
  const int tid = threadIdx.x;
  const int i0  = blockIdx.x * TROWS;
  if (blockIdx.x == 0 && tid == 0) out[0] = 0.0f;  // re-zero accumulator every launch

  __shared__ float sW2[128 * 128];       // 64 KB, fw2 row-major [k][f]
  __shared__ float sH[TROWS][128];       // 16 KB, hidden activations

  #pragma unroll
  for (int t = 0; t < 16; ++t) {
    const int e = tid + t * 256;
    ((float4*)sW2)[e] = ((const float4*)fw2)[e];
  }

  // phase 1: H[row][f] = ssp(gauss(r_row) . fw1[:,f] + fb1[f])
  {
    const int f  = tid & 127;
    const int rh = (tid >> 7) * (TROWS / 2);
    const float delta = RCUT / (float)(N_GAUSS - 1);
    const float coeff = -0.5f / (delta * delta);
    const float b1v = fb1[f];
    for (int j = 0; j < TROWS / 2; ++j) {
      const float r = (float)(i0 + rh + j) * (RCUT / (float)(TT - 1));
      float h = b1v;
      #pragma unroll
      for (int g = 0; g < N_GAUSS; ++g) {
        const float d = r - (float)g * delta;
        h = fmaf(__expf(coeff * d * d), fw1[g * 128 + f], h);
      }
      sH[rh + j][f] = ssp(h);
    }
  }
  __syncthreads();

  // phase 2: tab[row][c] = H[row][:] @ fw2[:,c] + fb2[c]
  {
    const int c0 = (tid & 31) * 4;
    const int rg = (tid >> 5) * 4;
    f32x4 acc[4];
    const float4 bv = *(const float4*)&fb2[c0];
    #pragma unroll
    for (int j = 0; j < 4; ++j) acc[j] = (f32x4){bv.x, bv.y, bv.z, bv.w};
    for (int k = 0; k < 128; ++k) {
      const float4 wv = *(const float4*)&sW2[k * 128 + c0];
      #pragma unroll
      for (int j = 0; j < 4; ++j) {
        const float hv = sH[rg + j][k];
        acc[j][0] = fmaf(hv, wv.x, acc[j][0]);
        acc[j][1] = fmaf(hv, wv.y, acc[j][1]);
        acc[j][2] = fmaf(hv, wv.z, acc[j][2]);
        acc[j][3] = fmaf(hv, wv.w, acc[j][3]);
      }
    }
    #pragma unroll
    for (int j = 0; j < 4; ++j) {
      const int i = i0 + rg + j;
      const float r = (float)i * (RCUT / (float)(TT - 1));
      const float fc = (r < RCUT) ? 0.5f * (__cosf(r * PI_F / RCUT) + 1.0f) : 0.0f;
      f16x4 o;
      #pragma unroll
      for (int c = 0; c < 4; ++c) o[c] = (f16)(acc[j][c] * fc);
      *(f16x4*)&tabh[i * 128 + c0] = o;
    }
  }
}

// ---- prep 2 (merged): weight transposes + ytab[z] = embed[z] @ in2f (100 rows)
__global__ void prep_merged_kernel(const float* __restrict__ w1,
                                   const float* __restrict__ w2,
                                   const float* __restrict__ mw1,
                                   const float* __restrict__ embed,
                                   const float* __restrict__ in2f,
                                   f16* __restrict__ w1ht,
                                   f16* __restrict__ w2ht,
                                   f16* __restrict__ mw1ht,
                                   f16* __restrict__ ytab) {
  const int c = blockIdx.x;    // output column / z index
  const int i = threadIdx.x;   // input row
  w1ht[c * 128 + i] = (f16)w1[i * 128 + c];
  w2ht[c * 128 + i] = (f16)w2[i * 128 + c];
  if (c < 64) mw1ht[c * 128 + i] = (f16)mw1[i * 64 + c];
  if (c < MAXZ) {              // uniform per block -> barrier is safe
    __shared__ float xs[128];
    xs[i] = embed[c * 128 + i];
    __syncthreads();
    float acc = 0.0f;
    for (int j = 0; j < 128; j += 4) {
      const float4 xv = *reinterpret_cast<const float4*>(&xs[j]);
      acc = fmaf(xv.x, in2f[(j + 0) * 128 + i], acc);
      acc = fmaf(xv.y, in2f[(j + 1) * 128 + i], acc);
      acc = fmaf(xv.z, in2f[(j + 2) * 128 + i], acc);
      acc = fmaf(xv.w, in2f[(j + 3) * 128 + i], acc);
    }
    ytab[c * 128 + i] = (f16)acc;
  }
}

// ---- main fused kernel: 256 threads, 16 atoms/block ----
__global__ void __launch_bounds__(256, 3)
schnet_main_kernel(const float* __restrict__ dR,
                   const int* __restrict__ Z,
                   const int* __restrict__ nbr,
                   const float* __restrict__ embed,
                   const f16* __restrict__ tabh,
                   const f16* __restrict__ ytab,
                   const f16* __restrict__ w1ht, const float* __restrict__ b1,
                   const f16* __restrict__ w2ht, const float* __restrict__ b2,
                   const f16* __restrict__ mw1ht, const float* __restrict__ mb1,
                   const float* __restrict__ mw2, const float* __restrict__ mb2,
                   float* __restrict__ out) {
  const int tid = threadIdx.x;
  const int wv  = tid >> 6;          // wave 0..3
  const int l   = tid & 63;
  const int a0  = blockIdx.x * 16;
  __shared__ __align__(16) int2 s_pk[16 * N_NBRS];   // 4 KB: {tab_row_byte, yt_lds_byte}
  __shared__ __align__(16) f16  syt[MAXZ * 128];     // 25.6 KB: full ytab
  __shared__ __align__(16) f16  sA[16 * 128];        // 4 KB swizzled activations
  __shared__ __align__(16) f16  sB[16 * 128];        // 4 KB swizzled activations
  __shared__ int   sZ[16];
  __shared__ float sRed[4];

  // -- stage ytab -> LDS (coalesced uint4) --
  for (int t = tid; t < MAXZ * 128 / 8; t += 256) {
    ((uint4*)syt)[t] = ((const uint4*)ytab)[t];
  }
  // -- stage per-pair row offsets (coalesced dR/nbr; Z gather L2-hit) --
  const float scale = (float)(TT - 1) / RCUT;
  #pragma unroll
  for (int t0 = 0; t0 < 2; ++t0) {
    const int t = tid + t0 * 256;
    const float r = dR[a0 * N_NBRS + t];
    const int  nb = nbr[a0 * N_NBRS + t];
    int i0 = (int)(r * scale + 0.5f);
    i0 = min(i0, TT - 1);
    const int z = Z[nb];
    s_pk[t] = make_int2(i0 << 8, z << 8);   // 256 B per row (128 x f16)
  }
  if (tid < 16) sZ[tid] = Z[a0 + tid];
  __syncthreads();

  // -- cfconv: wave owns atoms m0..m0+3; quarter-wave q owns k = 4s+q;
  //    lane covers 8 channels (16 B) per load; table=global, y=LDS.
  //    Two named banks x 4 slots, all trip-4 unrolls -> constant indices. --
  const int m0 = wv * 4;
  const int q  = l >> 4;          // quarter 0..3
  const int cq = l & 15;
  const int cq16 = cq * 16;       // 8 ch * 2 B
  const char* tbase = (const char*)tabh + cq16;
  const char* ybase = (const char*)syt + cq16;

  f16x2 acc[4][4];
  #pragma unroll
  for (int j = 0; j < 4; ++j) {
    #pragma unroll
    for (int c = 0; c < 4; ++c) acc[j][c] = (f16x2)0;
  }

  uint4 twA[4], ytA[4], twB[4], ytB[4];

  // slot s in [0,32): atom j = s>>3, k = (s&7)*4 + q
#define IG(BANK, g) { \
    _Pragma("unroll") \
    for (int d = 0; d < 4; ++d) { \
      const int s = (g) * 4 + d; \
      const int2 pk = s_pk[(m0 + (s >> 3)) * N_NBRS + ((s & 7) * 4 + q)]; \
      tw##BANK[d] = *(const uint4*)(tbase + pk.x); \
      yt##BANK[d] = *(const uint4*)(ybase + pk.y); \
    } }

#define CG(BANK, g) { \
    _Pragma("unroll") \
    for (int d = 0; d < 4; ++d) { \
      const int s = (g) * 4 + d; \
      const int j = s >> 3; \
      acc[j][0] += bch(tw##BANK[d].x) * bch(yt##BANK[d].x); \
      acc[j][1] += bch(tw##BANK[d].y) * bch(yt##BANK[d].y); \
      acc[j][2] += bch(tw##BANK[d].z) * bch(yt##BANK[d].z); \
      acc[j][3] += bch(tw##BANK[d].w) * bch(yt##BANK[d].w); \
    } }

  IG(A, 0) IG(B, 1)
  CG(A, 0) IG(A, 2)
  CG(B, 1) IG(B, 3)
  CG(A, 2) IG(A, 4)
  CG(B, 3) IG(B, 5)
  CG(A, 4) IG(A, 6)
  CG(B, 5) IG(B, 7)
  CG(A, 6)
  CG(B, 7)
#undef IG
#undef CG

  // combine across quarters (packed adds over bit-cast shuffles)
  #pragma unroll
  for (int j = 0; j < 4; ++j) {
    #pragma unroll
    for (int c = 0; c < 4; ++c) {
      uint_t u = hcb(acc[j][c]);
      const uint_t o1 = __shfl_xor(u, 16, 64);
      u = hcb(bch(u) + bch(o1));
      const uint_t o2 = __shfl_xor(u, 32, 64);
      acc[j][c] = bch(u) + bch(o2);
    }
  }
  if (q == 0) {
    #pragma unroll
    for (int j = 0; j < 4; ++j) {
      const int m = m0 + j;
      uint4 pkv;
      pkv.x = hcb(acc[j][0]);
      pkv.y = hcb(acc[j][1]);
      pkv.z = hcb(acc[j][2]);
      pkv.w = hcb(acc[j][3]);
      *(uint4*)&sA[m * 128 + (((cq ^ m) & 15) << 3)] = pkv;
    }
  }
  __syncthreads();

  const int rc = l & 15;
  const int qk = l >> 4;
#define AFRAG(SRC, k0) (*(const f16x8*)&SRC[rc * 128 + (((((k0) >> 3) + qk) ^ rc) & 15) * 8])

  // -- f2out layer 1: h1 = ssp(agg @ w1 + b1); wave covers cols wv*32..+31 --
  f32x4 dacc[2];
  #pragma unroll
  for (int t = 0; t < 2; ++t) {
    const float b = b1[wv * 32 + t * 16 + rc];
    dacc[t] = (f32x4){b, b, b, b};
  }
  #pragma unroll
  for (int k0 = 0; k0 < 128; k0 += 32) {
    const f16x8 af = AFRAG(sA, k0);
    #pragma unroll
    for (int t = 0; t < 2; ++t) {
      const int c = wv * 32 + t * 16 + rc;
      const f16x8 bf = *(const f16x8*)&w1ht[c * 128 + k0 + qk * 8];
      dacc[t] = __builtin_amdgcn_mfma_f32_16x16x32_f16(af, bf, dacc[t], 0, 0, 0);
    }
  }
  #pragma unroll
  for (int t = 0; t < 2; ++t) {
    const int c = wv * 32 + t * 16 + rc;
    #pragma unroll
    for (int r = 0; r < 4; ++r) {
      sB[swz(qk * 4 + r, c)] = (f16)ssp(dacc[t][r]);
    }
  }
  __syncthreads();

  // -- f2out layer 2 + residual: xnew = embed[Z] + (h1 @ w2 + b2) --
  #pragma unroll
  for (int t = 0; t < 2; ++t) {
    const float b = b2[wv * 32 + t * 16 + rc];
    dacc[t] = (f32x4){b, b, b, b};
  }
  #pragma unroll
  for (int k0 = 0; k0 < 128; k0 += 32) {
    const f16x8 af = AFRAG(sB, k0);
    #pragma unroll
    for (int t = 0; t < 2; ++t) {
      const int c = wv * 32 + t * 16 + rc;
      const f16x8 bf = *(const f16x8*)&w2ht[c * 128 + k0 + qk * 8];
      dacc[t] = __builtin_amdgcn_mfma_f32_16x16x32_f16(af, bf, dacc[t], 0, 0, 0);
    }
  }
  __syncthreads();   // all sB reads done before sA overwrite below
  #pragma unroll
  for (int t = 0; t < 2; ++t) {
    const int c = wv * 32 + t * 16 + rc;
    #pragma unroll
    for (int r = 0; r < 4; ++r) {
      const int m = qk * 4 + r;
      const float x = embed[(size_t)sZ[m] * 128 + c] + dacc[t][r];
      sA[swz(m, c)] = (f16)x;
    }
  }
  __syncthreads();

  // -- MLP layer 1: 128 -> 64; wave covers cols wv*16..+15 --
  const int c1 = wv * 16 + rc;
  const float bm = mb1[c1];
  f32x4 a2 = (f32x4){bm, bm, bm, bm};
  #pragma unroll
  for (int k0 = 0; k0 < 128; k0 += 32) {
    const f16x8 af = AFRAG(sA, k0);
    const f16x8 bf = *(const f16x8*)&mw1ht[c1 * 128 + k0 + qk * 8];
    a2 = __builtin_amdgcn_mfma_f32_16x16x32_f16(af, bf, a2, 0, 0, 0);
  }

  // -- MLP layer 2 (64 -> 1) + global sum --
  const float cm = mw2[c1];
  float v = 0.0f;
  #pragma unroll
  for (int r = 0; r < 4; ++r) v = fmaf(ssp(a2[r]), cm, v);
  #pragma unroll
  for (int o = 1; o < 64; o <<= 1) v += __shfl_xor(v, o, 64);
  if (l == 0) sRed[wv] = v;
  __syncthreads();
  if (tid == 0) {
    atomicAdd(out, 20.0f * (sRed[0] + sRed[1] + sRed[2] + sRed[3] + 16.0f * mb2[0]));
  }
#undef AFRAG
}

extern "C" void kernel_launch(void* const* d_in, const int* in_sizes, int n_in,
                              void* d_out, int out_size, void* d_ws, size_t ws_size,
                              hipStream_t stream) {
  const float* dR    = (const float*)d_in[0];
  const int*   Z     = (const int*)  d_in[1];
  const int*   nbr   = (const int*)  d_in[2];
  const float* embed = (const float*)d_in[3];
  const float* fw1   = (const float*)d_in[4];
  const float* fb1   = (const float*)d_in[5];
  const float* fw2   = (const float*)d_in[6];
  const float* fb2   = (const float*)d_in[7];
  const float* in2f  = (const float*)d_in[8];
  const float* w1    = (const float*)d_in[9];
  const float* b1    = (const float*)d_in[10];
  const float* w2    = (const float*)d_in[11];
  const float* b2    = (const float*)d_in[12];
  const float* mw1   = (const float*)d_in[13];
  const float* mb1   = (const float*)d_in[14];
  const float* mw2   = (const float*)d_in[15];
  const float* mb2   = (const float*)d_in[16];
  float* out = (float*)d_out;

  char* ws = (char*)d_ws;
  f16* tabh  = (f16*)ws;                                   // 1 MB
  f16* ytab  = (f16*)(ws + (size_t)1088 * 1024);           // 25.6 KB
  f16* w1ht  = (f16*)(ws + (size_t)1152 * 1024);           // 32 KB
  f16* w2ht  = (f16*)(ws + (size_t)1216 * 1024);           // 32 KB
  f16* mw1ht = (f16*)(ws + (size_t)1280 * 1024);           // 16 KB

  build_table_kernel<<<TT / TROWS, 256, 0, stream>>>(fw1, fb1, fw2, fb2, tabh, out);
  prep_merged_kernel<<<128, 128, 0, stream>>>(w1, w2, mw1, embed, in2f,
                                              w1ht, w2ht, mw1ht, ytab);
  schnet_main_kernel<<<N_ATOMS / 16, 256, 0, stream>>>(dR, Z, nbr, embed,
      tabh, ytab, w1ht, b1, w2ht, b2, mw1ht, mb1, mw2, mb2, out);
}

// Round 9
// 79.564 us; speedup vs baseline: 4.1402x; 1.0404x over previous
//
#include <hip/hip_runtime.h>
#include <math.h>

#define N_ATOMS  50000
#define N_NBRS   32
#define N_GAUSS  25
#define RCUT     5.0f
#define TT       1024      // nearest-neighbor filter table nodes
#define TROWS    32        // table rows per build block
#define NTB      (TT / TROWS)   // 32 table-build blocks
#define MAXZ     100
#define PI_F     3.14159265358979323846f

typedef unsigned int   uint_t;
typedef unsigned short ushort_t;
typedef _Float16 f16;
typedef f16   f16x2 __attribute__((ext_vector_type(2)));
typedef f16   f16x4 __attribute__((ext_vector_type(4)));
typedef f16   f16x8 __attribute__((ext_vector_type(8)));
typedef float f32x4 __attribute__((ext_vector_type(4)));

// fast shifted softplus: max(x,0) + log(0.5 + 0.5*exp(-|x|))  (== softplus(x)-log2)
__device__ __forceinline__ float ssp(float x) {
  return fmaxf(x, 0.0f) + __logf(fmaf(0.5f, __expf(-fabsf(x)), 0.5f));
}
__device__ __forceinline__ f16x2 bch(uint_t u) {
  return __builtin_bit_cast(f16x2, u);
}
__device__ __forceinline__ uint_t hcb(f16x2 v) {
  return __builtin_bit_cast(uint_t, v);
}
// swizzled element offset into a [16][128] f16 LDS tile (8-elem chunk XOR row)
__device__ __forceinline__ int swz(int m, int e) {
  return m * 128 + ((((e >> 3) ^ m) & 15) << 3) + (e & 7);
}

// ---- single prep dispatch:
//   blocks [0, NTB):      nearest table tabh[i][f] = f16(W(r_i)*fcut(r_i))
//   blocks [NTB, NTB+64): weight transposes (2 cols/block) + ytab rows
__global__ void __launch_bounds__(256, 2)
prep_all_kernel(const float* __restrict__ fw1,
                const float* __restrict__ fb1,
                const float* __restrict__ fw2,
                const float* __restrict__ fb2,
                const float* __restrict__ w1,
                const float* __restrict__ w2,
                const float* __restrict__ mw1,
                const float* __restrict__ embed,
                const float* __restrict__ in2f,
                f16* __restrict__ tabh,
                f16* __restrict__ ytab,
                f16* __restrict__ w1ht,
                f16* __restrict__ w2ht,
                f16* __restrict__ mw1ht,
                float* __restrict__ out) {
  const int tid = threadIdx.x;
  const int bid = blockIdx.x;
  if (bid == 0 && tid == 0) out[0] = 0.0f;   // re-zero accumulator every launch

  __shared__ float sW2[128 * 128];       // 64 KB
  __shared__ float sH[TROWS][128];       // 16 KB

  if (bid < NTB) {
    // ---- table build path ----
    const int i0 = bid * TROWS;
    #pragma unroll
    for (int t = 0; t < 16; ++t) {
      const int e = tid + t * 256;
      ((float4*)sW2)[e] = ((const float4*)fw2)[e];
    }
    // phase 1: H[row][f] = ssp(gauss(r_row) . fw1[:,f] + fb1[f])
    {
      const int f  = tid & 127;
      const int rh = (tid >> 7) * (TROWS / 2);
      const float delta = RCUT / (float)(N_GAUSS - 1);
      const float coeff = -0.5f / (delta * delta);
      const float b1v = fb1[f];
      for (int j = 0; j < TROWS / 2; ++j) {
        const float r = (float)(i0 + rh + j) * (RCUT / (float)(TT - 1));
        float h = b1v;
        #pragma unroll
        for (int g = 0; g < N_GAUSS; ++g) {
          const float d = r - (float)g * delta;
          h = fmaf(__expf(coeff * d * d), fw1[g * 128 + f], h);
        }
        sH[rh + j][f] = ssp(h);
      }
    }
    __syncthreads();
    // phase 2: tab[row][c] = H[row][:] @ fw2[:,c] + fb2[c]
    {
      const int c0 = (tid & 31) * 4;
      const int rg = (tid >> 5) * 4;
      f32x4 acc[4];
      const float4 bv = *(const float4*)&fb2[c0];
      #pragma unroll
      for (int j = 0; j < 4; ++j) acc[j] = (f32x4){bv.x, bv.y, bv.z, bv.w};
      for (int k = 0; k < 128; ++k) {
        const float4 wv = *(const float4*)&sW2[k * 128 + c0];
        #pragma unroll
        for (int j = 0; j < 4; ++j) {
          const float hv = sH[rg + j][k];
          acc[j][0] = fmaf(hv, wv.x, acc[j][0]);
          acc[j][1] = fmaf(hv, wv.y, acc[j][1]);
          acc[j][2] = fmaf(hv, wv.z, acc[j][2]);
          acc[j][3] = fmaf(hv, wv.w, acc[j][3]);
        }
      }
      #pragma unroll
      for (int j = 0; j < 4; ++j) {
        const int i = i0 + rg + j;
        const float r = (float)i * (RCUT / (float)(TT - 1));
        const float fc = (r < RCUT) ? 0.5f * (__cosf(r * PI_F / RCUT) + 1.0f) : 0.0f;
        f16x4 o;
        #pragma unroll
        for (int c = 0; c < 4; ++c) o[c] = (f16)(acc[j][c] * fc);
        *(f16x4*)&tabh[i * 128 + c0] = o;
      }
    }
  } else {
    // ---- weight transpose + ytab path (2 output cols per block) ----
    const int cc = (bid - NTB) * 2 + (tid >> 7);
    const int i  = tid & 127;
    w1ht[cc * 128 + i] = (f16)w1[i * 128 + cc];
    w2ht[cc * 128 + i] = (f16)w2[i * 128 + cc];
    if (cc < 64) mw1ht[cc * 128 + i] = (f16)mw1[i * 64 + cc];
    float* xs = &sH[0][0] + (tid >> 7) * 128;   // reuse sH as two x rows
    xs[i] = (cc < MAXZ) ? embed[cc * 128 + i] : 0.0f;
    __syncthreads();
    if (cc < MAXZ) {
      float acc = 0.0f;
      for (int j = 0; j < 128; j += 4) {
        const float4 xv = *reinterpret_cast<const float4*>(&xs[j]);
        acc = fmaf(xv.x, in2f[(j + 0) * 128 + i], acc);
        acc = fmaf(xv.y, in2f[(j + 1) * 128 + i], acc);
        acc = fmaf(xv.z, in2f[(j + 2) * 128 + i], acc);
        acc = fmaf(xv.w, in2f[(j + 3) * 128 + i], acc);
      }
      ytab[cc * 128 + i] = (f16)acc;
    }
  }
}

// ---- main fused kernel: 256 threads, 16 atoms/block ----
__global__ void __launch_bounds__(256, 6)
schnet_main_kernel(const float* __restrict__ dR,
                   const int* __restrict__ Z,
                   const int* __restrict__ nbr,
                   const float* __restrict__ embed,
                   const f16* __restrict__ tabh,
                   const f16* __restrict__ ytab,
                   const f16* __restrict__ w1ht, const float* __restrict__ b1,
                   const f16* __restrict__ w2ht, const float* __restrict__ b2,
                   const f16* __restrict__ mw1ht, const float* __restrict__ mb1,
                   const float* __restrict__ mw2, const float* __restrict__ mb2,
                   float* __restrict__ out) {
  const int tid = threadIdx.x;
  const int wv  = tid >> 6;          // wave 0..3
  const int l   = tid & 63;
  const int a0  = blockIdx.x * 16;
  __shared__ __align__(16) int2 s_pk[16 * N_NBRS];   // 4 KB: {tab_row_byte, ytab_row_byte}
  __shared__ __align__(16) f16  sA[16 * 128];        // 4 KB swizzled activations
  __shared__ __align__(16) f16  sB[16 * 128];        // 4 KB swizzled activations
  __shared__ int   sZ[16];
  __shared__ float sRed[4];

  // -- stage per-pair row offsets (coalesced dR/nbr; Z gather L2-hit) --
  const float scale = (float)(TT - 1) / RCUT;
  #pragma unroll
  for (int t0 = 0; t0 < 2; ++t0) {
    const int t = tid + t0 * 256;
    const float r = dR[a0 * N_NBRS + t];
    const int  nb = nbr[a0 * N_NBRS + t];
    int i0 = (int)(r * scale + 0.5f);
    i0 = min(i0, TT - 1);
    const int z = Z[nb];
    s_pk[t] = make_int2(i0 << 8, z << 8);   // 256 B per row (128 x f16)
  }
  if (tid < 16) sZ[tid] = Z[a0 + tid];
  __syncthreads();

  // -- cfconv: wave owns atoms m0..m0+3; quarter-wave q owns k = 4s+q;
  //    lane covers 8 channels (16 B) per load; both table and y rows from
  //    global (table 256 KB L2, ytab 25.6 KB L1-resident), coalesced per quarter.
  //    Two named banks x 4 slots, all trip-4 unrolls -> constant indices. --
  const int m0 = wv * 4;
  const int q  = l >> 4;          // quarter 0..3
  const int cq = l & 15;
  const int cq16 = cq * 16;       // 8 ch * 2 B
  const char* tbase = (const char*)tabh + cq16;
  const char* ybase = (const char*)ytab + cq16;

  f16x2 acc[4][4];
  #pragma unroll
  for (int j = 0; j < 4; ++j) {
    #pragma unroll
    for (int c = 0; c < 4; ++c) acc[j][c] = (f16x2)0;
  }

  uint4 twA[4], ytA[4], twB[4], ytB[4];

  // slot s in [0,32): atom j = s>>3, k = (s&7)*4 + q
#define IG(BANK, g) { \
    _Pragma("unroll") \
    for (int d = 0; d < 4; ++d) { \
      const int s = (g) * 4 + d; \
      const int2 pk = s_pk[(m0 + (s >> 3)) * N_NBRS + ((s & 7) * 4 + q)]; \
      tw##BANK[d] = *(const uint4*)(tbase + pk.x); \
      yt##BANK[d] = *(const uint4*)(ybase + pk.y); \
    } }

#define CG(BANK, g) { \
    _Pragma("unroll") \
    for (int d = 0; d < 4; ++d) { \
      const int s = (g) * 4 + d; \
      const int j = s >> 3; \
      acc[j][0] += bch(tw##BANK[d].x) * bch(yt##BANK[d].x); \
      acc[j][1] += bch(tw##BANK[d].y) * bch(yt##BANK[d].y); \
      acc[j][2] += bch(tw##BANK[d].z) * bch(yt##BANK[d].z); \
      acc[j][3] += bch(tw##BANK[d].w) * bch(yt##BANK[d].w); \
    } }

  IG(A, 0) IG(B, 1)
  CG(A, 0) IG(A, 2)
  CG(B, 1) IG(B, 3)
  CG(A, 2) IG(A, 4)
  CG(B, 3) IG(B, 5)
  CG(A, 4) IG(A, 6)
  CG(B, 5) IG(B, 7)
  CG(A, 6)
  CG(B, 7)
#undef IG
#undef CG

  // combine across quarters (packed adds over bit-cast shuffles)
  #pragma unroll
  for (int j = 0; j < 4; ++j) {
    #pragma unroll
    for (int c = 0; c < 4; ++c) {
      uint_t u = hcb(acc[j][c]);
      const uint_t o1 = __shfl_xor(u, 16, 64);
      u = hcb(bch(u) + bch(o1));
      const uint_t o2 = __shfl_xor(u, 32, 64);
      acc[j][c] = bch(u) + bch(o2);
    }
  }
  if (q == 0) {
    #pragma unroll
    for (int j = 0; j < 4; ++j) {
      const int m = m0 + j;
      uint4 pkv;
      pkv.x = hcb(acc[j][0]);
      pkv.y = hcb(acc[j][1]);
      pkv.z = hcb(acc[j][2]);
      pkv.w = hcb(acc[j][3]);
      *(uint4*)&sA[m * 128 + (((cq ^ m) & 15) << 3)] = pkv;
    }
  }
  __syncthreads();

  const int rc = l & 15;
  const int qk = l >> 4;
#define AFRAG(SRC, k0) (*(const f16x8*)&SRC[rc * 128 + (((((k0) >> 3) + qk) ^ rc) & 15) * 8])

  // -- f2out layer 1: h1 = ssp(agg @ w1 + b1); wave covers cols wv*32..+31 --
  f32x4 dacc[2];
  #pragma unroll
  for (int t = 0; t < 2; ++t) {
    const float b = b1[wv * 32 + t * 16 + rc];
    dacc[t] = (f32x4){b, b, b, b};
  }
  #pragma unroll
  for (int k0 = 0; k0 < 128; k0 += 32) {
    const f16x8 af = AFRAG(sA, k0);
    #pragma unroll
    for (int t = 0; t < 2; ++t) {
      const int c = wv * 32 + t * 16 + rc;
      const f16x8 bf = *(const f16x8*)&w1ht[c * 128 + k0 + qk * 8];
      dacc[t] = __builtin_amdgcn_mfma_f32_16x16x32_f16(af, bf, dacc[t], 0, 0, 0);
    }
  }
  #pragma unroll
  for (int t = 0; t < 2; ++t) {
    const int c = wv * 32 + t * 16 + rc;
    #pragma unroll
    for (int r = 0; r < 4; ++r) {
      sB[swz(qk * 4 + r, c)] = (f16)ssp(dacc[t][r]);
    }
  }
  __syncthreads();

  // -- f2out layer 2 + residual: xnew = embed[Z] + (h1 @ w2 + b2) --
  #pragma unroll
  for (int t = 0; t < 2; ++t) {
    const float b = b2[wv * 32 + t * 16 + rc];
    dacc[t] = (f32x4){b, b, b, b};
  }
  #pragma unroll
  for (int k0 = 0; k0 < 128; k0 += 32) {
    const f16x8 af = AFRAG(sB, k0);
    #pragma unroll
    for (int t = 0; t < 2; ++t) {
      const int c = wv * 32 + t * 16 + rc;
      const f16x8 bf = *(const f16x8*)&w2ht[c * 128 + k0 + qk * 8];
      dacc[t] = __builtin_amdgcn_mfma_f32_16x16x32_f16(af, bf, dacc[t], 0, 0, 0);
    }
  }
  __syncthreads();   // all sB reads done before sA overwrite below
  #pragma unroll
  for (int t = 0; t < 2; ++t) {
    const int c = wv * 32 + t * 16 + rc;
    #pragma unroll
    for (int r = 0; r < 4; ++r) {
      const int m = qk * 4 + r;
      const float x = embed[(size_t)sZ[m] * 128 + c] + dacc[t][r];
      sA[swz(m, c)] = (f16)x;
    }
  }
  __syncthreads();

  // -- MLP layer 1: 128 -> 64; wave covers cols wv*16..+15 --
  const int c1 = wv * 16 + rc;
  const float bm = mb1[c1];
  f32x4 a2 = (f32x4){bm, bm, bm, bm};
  #pragma unroll
  for (int k0 = 0; k0 < 128; k0 += 32) {
    const f16x8 af = AFRAG(sA, k0);
    const f16x8 bf = *(const f16x8*)&mw1ht[c1 * 128 + k0 + qk * 8];
    a2 = __builtin_amdgcn_mfma_f32_16x16x32_f16(af, bf, a2, 0, 0, 0);
  }

  // -- MLP layer 2 (64 -> 1) + global sum --
  const float cm = mw2[c1];
  float v = 0.0f;
  #pragma unroll
  for (int r = 0; r < 4; ++r) v = fmaf(ssp(a2[r]), cm, v);
  #pragma unroll
  for (int o = 1; o < 64; o <<= 1) v += __shfl_xor(v, o, 64);
  if (l == 0) sRed[wv] = v;
  __syncthreads();
  if (tid == 0) {
    atomicAdd(out, 20.0f * (sRed[0] + sRed[1] + sRed[2] + sRed[3] + 16.0f * mb2[0]));
  }
#undef AFRAG
}

extern "C" void kernel_launch(void* const* d_in, const int* in_sizes, int n_in,
                              void* d_out, int out_size, void* d_ws, size_t ws_size,
                              hipStream_t stream) {
  const float* dR    = (const float*)d_in[0];
  const int*   Z     = (const int*)  d_in[1];
  const int*   nbr   = (const int*)  d_in[2];
  const float* embed = (const float*)d_in[3];
  const float* fw1   = (const float*)d_in[4];
  const float* fb1   = (const float*)d_in[5];
  const float* fw2   = (const float*)d_in[6];
  const float* fb2   = (const float*)d_in[7];
  const float* in2f  = (const float*)d_in[8];
  const float* w1    = (const float*)d_in[9];
  const float* b1    = (const float*)d_in[10];
  const float* w2    = (const float*)d_in[11];
  const float* b2    = (const float*)d_in[12];
  const float* mw1   = (const float*)d_in[13];
  const float* mb1   = (const float*)d_in[14];
  const float* mw2   = (const float*)d_in[15];
  const float* mb2   = (const float*)d_in[16];
  float* out = (float*)d_out;

  char* ws = (char*)d_ws;
  f16* tabh  = (f16*)ws;                                   // 256 KB (TT=1024)
  f16* ytab  = (f16*)(ws + (size_t)512 * 1024);            // 25.6 KB
  f16* w1ht  = (f16*)(ws + (size_t)576 * 1024);            // 32 KB
  f16* w2ht  = (f16*)(ws + (size_t)640 * 1024);            // 32 KB
  f16* mw1ht = (f16*)(ws + (size_t)704 * 1024);            // 16 KB

  prep_all_kernel<<<NTB + 64, 256, 0, stream>>>(fw1, fb1, fw2, fb2,
      w1, w2, mw1, embed, in2f, tabh, ytab, w1ht, w2ht, mw1ht, out);
  schnet_main_kernel<<<N_ATOMS / 16, 256, 0, stream>>>(dR, Z, nbr, embed,
      tabh, ytab, w1ht, b1, w2ht, b2, mw1ht, mb1, mw2, mb2, out);
}

// Round 10
// 78.339 us; speedup vs baseline: 4.2049x; 1.0156x over previous
//
#include <hip/hip_runtime.h>
#include <math.h>

#define N_ATOMS  50000
#define N_NBRS   32
#define N_GAUSS  25
#define RCUT     5.0f
#define TTN      385       // lerp table nodes (384 intervals); node i at r = i*5/384
#define TROWS    32        // table rows per build block
#define NTB      13        // ceil(385/32) build blocks
#define MAXZ     100
#define NTILES   (N_ATOMS / 16)   // 3125 atom-tiles of 16
#define PBLOCKS  256       // persistent blocks (1 per CU)
#define PI_F     3.14159265358979323846f

typedef unsigned int   uint_t;
typedef unsigned short ushort_t;
typedef _Float16 f16;
typedef f16   f16x2 __attribute__((ext_vector_type(2)));
typedef f16   f16x4 __attribute__((ext_vector_type(4)));
typedef f16   f16x8 __attribute__((ext_vector_type(8)));
typedef float f32x4 __attribute__((ext_vector_type(4)));

// fast shifted softplus: max(x,0) + log(0.5 + 0.5*exp(-|x|))  (== softplus(x)-log2)
__device__ __forceinline__ float ssp(float x) {
  return fmaxf(x, 0.0f) + __logf(fmaf(0.5f, __expf(-fabsf(x)), 0.5f));
}
__device__ __forceinline__ f16x2 bch(uint_t u) {
  return __builtin_bit_cast(f16x2, u);
}
__device__ __forceinline__ uint_t hcb(f16x2 v) {
  return __builtin_bit_cast(uint_t, v);
}
// swizzled element offset into a [16][128] f16 LDS tile (8-elem chunk XOR row)
__device__ __forceinline__ int swz(int m, int e) {
  return m * 128 + ((((e >> 3) ^ m) & 15) << 3) + (e & 7);
}

// ---- single prep dispatch:
//   blocks [0, NTB):      lerp table tabh[i][f] = f16(W(r_i)*fcut(r_i)), i<385
//   blocks [NTB, NTB+64): weight transposes (2 cols/block) + ytab rows
__global__ void __launch_bounds__(256, 2)
prep_all_kernel(const float* __restrict__ fw1,
                const float* __restrict__ fb1,
                const float* __restrict__ fw2,
                const float* __restrict__ fb2,
                const float* __restrict__ w1,
                const float* __restrict__ w2,
                const float* __restrict__ mw1,
                const float* __restrict__ embed,
                const float* __restrict__ in2f,
                f16* __restrict__ tabh,
                f16* __restrict__ ytab,
                f16* __restrict__ w1ht,
                f16* __restrict__ w2ht,
                f16* __restrict__ mw1ht,
                float* __restrict__ out) {
  const int tid = threadIdx.x;
  const int bid = blockIdx.x;
  if (bid == 0 && tid == 0) out[0] = 0.0f;   // re-zero accumulator every launch

  __shared__ float sW2[128 * 128];       // 64 KB
  __shared__ float sH[TROWS][128];       // 16 KB

  if (bid < NTB) {
    // ---- table build path ----
    const int i0 = bid * TROWS;
    #pragma unroll
    for (int t = 0; t < 16; ++t) {
      const int e = tid + t * 256;
      ((float4*)sW2)[e] = ((const float4*)fw2)[e];
    }
    // phase 1: H[row][f] = ssp(gauss(r_row) . fw1[:,f] + fb1[f])
    {
      const int f  = tid & 127;
      const int rh = (tid >> 7) * (TROWS / 2);
      const float delta = RCUT / (float)(N_GAUSS - 1);
      const float coeff = -0.5f / (delta * delta);
      const float b1v = fb1[f];
      for (int j = 0; j < TROWS / 2; ++j) {
        const float r = (float)(i0 + rh + j) * (RCUT / 384.0f);
        float h = b1v;
        #pragma unroll
        for (int g = 0; g < N_GAUSS; ++g) {
          const float d = r - (float)g * delta;
          h = fmaf(__expf(coeff * d * d), fw1[g * 128 + f], h);
        }
        sH[rh + j][f] = ssp(h);
      }
    }
    __syncthreads();
    // phase 2: tab[row][c] = H[row][:] @ fw2[:,c] + fb2[c]
    {
      const int c0 = (tid & 31) * 4;
      const int rg = (tid >> 5) * 4;
      f32x4 acc[4];
      const float4 bv = *(const float4*)&fb2[c0];
      #pragma unroll
      for (int j = 0; j < 4; ++j) acc[j] = (f32x4){bv.x, bv.y, bv.z, bv.w};
      for (int k = 0; k < 128; ++k) {
        const float4 wv = *(const float4*)&sW2[k * 128 + c0];
        #pragma unroll
        for (int j = 0; j < 4; ++j) {
          const float hv = sH[rg + j][k];
          acc[j][0] = fmaf(hv, wv.x, acc[j][0]);
          acc[j][1] = fmaf(hv, wv.y, acc[j][1]);
          acc[j][2] = fmaf(hv, wv.z, acc[j][2]);
          acc[j][3] = fmaf(hv, wv.w, acc[j][3]);
        }
      }
      #pragma unroll
      for (int j = 0; j < 4; ++j) {
        const int i = i0 + rg + j;
        if (i < TTN) {
          const float r = (float)i * (RCUT / 384.0f);
          const float fc = (r < RCUT) ? 0.5f * (__cosf(r * PI_F / RCUT) + 1.0f) : 0.0f;
          f16x4 o;
          #pragma unroll
          for (int c = 0; c < 4; ++c) o[c] = (f16)(acc[j][c] * fc);
          *(f16x4*)&tabh[i * 128 + c0] = o;
        }
      }
    }
  } else {
    // ---- weight transpose + ytab path (2 output cols per block) ----
    const int cc = (bid - NTB) * 2 + (tid >> 7);
    const int i  = tid & 127;
    w1ht[cc * 128 + i] = (f16)w1[i * 128 + cc];
    w2ht[cc * 128 + i] = (f16)w2[i * 128 + cc];
    if (cc < 64) mw1ht[cc * 128 + i] = (f16)mw1[i * 64 + cc];
    float* xs = &sH[0][0] + (tid >> 7) * 128;   // reuse sH as two x rows
    xs[i] = (cc < MAXZ) ? embed[cc * 128 + i] : 0.0f;
    __syncthreads();
    if (cc < MAXZ) {
      float acc = 0.0f;
      for (int j = 0; j < 128; j += 4) {
        const float4 xv = *reinterpret_cast<const float4*>(&xs[j]);
        acc = fmaf(xv.x, in2f[(j + 0) * 128 + i], acc);
        acc = fmaf(xv.y, in2f[(j + 1) * 128 + i], acc);
        acc = fmaf(xv.z, in2f[(j + 2) * 128 + i], acc);
        acc = fmaf(xv.w, in2f[(j + 3) * 128 + i], acc);
      }
      ytab[cc * 128 + i] = (f16)acc;
    }
  }
}

// ---- main fused kernel: persistent, 512 threads (8 waves), 16 atoms/tile,
//      ALL gather tables LDS-resident, dense weights in registers ----
__global__ void __launch_bounds__(512, 2)
schnet_main_kernel(const float* __restrict__ dR,
                   const int* __restrict__ Z,
                   const int* __restrict__ nbr,
                   const float* __restrict__ embed,
                   const f16* __restrict__ tabh,
                   const f16* __restrict__ ytab,
                   const f16* __restrict__ w1ht, const float* __restrict__ b1,
                   const f16* __restrict__ w2ht, const float* __restrict__ b2,
                   const f16* __restrict__ mw1ht, const float* __restrict__ mb1,
                   const float* __restrict__ mw2, const float* __restrict__ mb2,
                   float* __restrict__ out) {
  const int tid = threadIdx.x;
  const int wvi = tid >> 6;          // wave 0..7
  const int l   = tid & 63;
  __shared__ __align__(16) f16  sW[TTN * 128];     // 98.56 KB lerp nodes
  __shared__ __align__(16) f16  sYT[MAXZ * 128];   // 25.6 KB y rows
  __shared__ __align__(16) int2 s_pk[512];         // 4 KB per-pair packs
  __shared__ __align__(16) f16  sA[16 * 128];      // 4 KB
  __shared__ __align__(16) f16  sB[16 * 128];      // 4 KB
  __shared__ int   sZ[16];
  __shared__ float sRed[4];

  // -- stage tables once (coalesced uint4) --
  for (int e = tid; e < TTN * 16; e += 512) ((uint4*)sW)[e] = ((const uint4*)tabh)[e];
  for (int e = tid; e < MAXZ * 16; e += 512) ((uint4*)sYT)[e] = ((const uint4*)ytab)[e];

  const int rc = l & 15;             // 0..15
  const int qk = l >> 4;             // 0..3 (quarter / k-subblock)
  const int cF = wvi * 16 + rc;      // this wave's dense output column

  // -- preload dense B-fragments (constant across tiles) --
  f16x8 bw1[4], bw2[4], bwm[4];
  #pragma unroll
  for (int k0i = 0; k0i < 4; ++k0i) {
    bw1[k0i] = *(const f16x8*)&w1ht[cF * 128 + k0i * 32 + qk * 8];
    bw2[k0i] = *(const f16x8*)&w2ht[cF * 128 + k0i * 32 + qk * 8];
    if (wvi < 4) bwm[k0i] = *(const f16x8*)&mw1ht[cF * 128 + k0i * 32 + qk * 8];
    else         bwm[k0i] = (f16x8)0;
  }
  const float b1v  = b1[cF];
  const float b2v  = b2[cF];
  const float bmv  = (wvi < 4) ? mb1[cF] : 0.0f;
  const float cmv  = (wvi < 4) ? mw2[cF] : 0.0f;
  const float mb2v = mb2[0];
  __syncthreads();

  const char* wb = (const char*)sW  + rc * 16;
  const char* yb = (const char*)sYT + rc * 16;
  const int m0 = wvi * 2;            // this wave's two atoms within the tile

#define AFRAG(SRC, k0) (*(const f16x8*)&SRC[rc * 128 + (((((k0) >> 3) + qk) ^ rc) & 15) * 8])

  for (int tile = blockIdx.x; tile < NTILES; tile += PBLOCKS) {
    const int a0 = tile * 16;

    // -- stage per-pair packs: {tab_byte | t12<<20, ytab_byte} --
    {
      const float r = dR[a0 * N_NBRS + tid];
      const int  nb = nbr[a0 * N_NBRS + tid];
      const float u = r * (384.0f / RCUT);
      int i0 = (int)u;
      i0 = min(i0, 383);
      const int t12 = (int)((u - (float)i0) * 4096.0f);
      s_pk[tid] = make_int2((i0 << 8) | (t12 << 20), Z[nb] << 8);
    }
    if (tid < 16) sZ[tid] = Z[a0 + tid];
    __syncthreads();

    // -- cfconv from LDS: slot s in [0,16): atom j=s>>3, k=(s&7)*4+qk --
    f16x2 acc[2][4];
    #pragma unroll
    for (int j = 0; j < 2; ++j)
      #pragma unroll
      for (int c = 0; c < 4; ++c) acc[j][c] = (f16x2)0;

    uint4 tLA[4], tHA[4], ytA[4]; float tfA[4];
    uint4 tLB[4], tHB[4], ytB[4]; float tfB[4];

#define IG(BK, g) { \
    _Pragma("unroll") \
    for (int d = 0; d < 4; ++d) { \
      const int s = (g) * 4 + d; \
      const int2 pk = s_pk[(m0 + (s >> 3)) * N_NBRS + ((s & 7) * 4 + qk)]; \
      const int off = pk.x & 0xFFFFF; \
      tL##BK[d] = *(const uint4*)(wb + off); \
      tH##BK[d] = *(const uint4*)(wb + off + 256); \
      yt##BK[d] = *(const uint4*)(yb + pk.y); \
      tf##BK[d] = (float)((uint_t)pk.x >> 20) * (1.0f / 4096.0f); \
    } }

#define CG(BK, g) { \
    _Pragma("unroll") \
    for (int d = 0; d < 4; ++d) { \
      const int s = (g) * 4 + d; \
      const int j = s >> 3; \
      const f16 tsc = (f16)tf##BK[d]; \
      const f16x2 tvv = {tsc, tsc}; \
      _Pragma("unroll") \
      for (int c = 0; c < 4; ++c) { \
        const f16x2 wl = bch(((const uint_t*)&tL##BK[d])[c]); \
        const f16x2 wh = bch(((const uint_t*)&tH##BK[d])[c]); \
        const f16x2 yv = bch(((const uint_t*)&yt##BK[d])[c]); \
        const f16x2 wf = wl + tvv * (wh - wl); \
        acc[j][c] += yv * wf; \
      } \
    } }

    IG(A, 0) IG(B, 1)
    CG(A, 0) IG(A, 2)
    CG(B, 1) IG(B, 3)
    CG(A, 2)
    CG(B, 3)
#undef IG
#undef CG

    // -- combine quarters (packed adds over bit-cast shuffles) --
    #pragma unroll
    for (int j = 0; j < 2; ++j)
      #pragma unroll
      for (int c = 0; c < 4; ++c) {
        uint_t u = hcb(acc[j][c]);
        u = hcb(bch(u) + bch(__shfl_xor(u, 16, 64)));
        acc[j][c] = bch(u) + bch(__shfl_xor(u, 32, 64));
      }
    if (qk == 0) {
      #pragma unroll
      for (int j = 0; j < 2; ++j) {
        const int m = m0 + j;
        uint4 pkv;
        pkv.x = hcb(acc[j][0]);
        pkv.y = hcb(acc[j][1]);
        pkv.z = hcb(acc[j][2]);
        pkv.w = hcb(acc[j][3]);
        *(uint4*)&sA[m * 128 + (((rc ^ m) & 15) << 3)] = pkv;
      }
    }
    __syncthreads();

    // -- f2out layer 1: each wave its 16 cols, B from registers --
    f32x4 d1 = (f32x4){b1v, b1v, b1v, b1v};
    #pragma unroll
    for (int k0i = 0; k0i < 4; ++k0i)
      d1 = __builtin_amdgcn_mfma_f32_16x16x32_f16(AFRAG(sA, k0i * 32), bw1[k0i], d1, 0, 0, 0);
    #pragma unroll
    for (int r = 0; r < 4; ++r) sB[swz(qk * 4 + r, cF)] = (f16)ssp(d1[r]);
    __syncthreads();

    // -- f2out layer 2 + residual --
    f32x4 d2 = (f32x4){b2v, b2v, b2v, b2v};
    #pragma unroll
    for (int k0i = 0; k0i < 4; ++k0i)
      d2 = __builtin_amdgcn_mfma_f32_16x16x32_f16(AFRAG(sB, k0i * 32), bw2[k0i], d2, 0, 0, 0);
    __syncthreads();   // all sB reads complete before sA overwrite races? (sA write next)
    #pragma unroll
    for (int r = 0; r < 4; ++r) {
      const int m = qk * 4 + r;
      const float x = embed[(size_t)sZ[m] * 128 + cF] + d2[r];
      sA[swz(m, cF)] = (f16)x;
    }
    __syncthreads();

    // -- MLP 128->64->1 (waves 0..3) + tile sum --
    float v = 0.0f;
    if (wvi < 4) {
      f32x4 dm = (f32x4){bmv, bmv, bmv, bmv};
      #pragma unroll
      for (int k0i = 0; k0i < 4; ++k0i)
        dm = __builtin_amdgcn_mfma_f32_16x16x32_f16(AFRAG(sA, k0i * 32), bwm[k0i], dm, 0, 0, 0);
      #pragma unroll
      for (int r = 0; r < 4; ++r) v = fmaf(ssp(dm[r]), cmv, v);
      #pragma unroll
      for (int o = 1; o < 64; o <<= 1) v += __shfl_xor(v, o, 64);
      if (l == 0) sRed[wvi] = v;
    }
    __syncthreads();
    if (tid == 0) {
      atomicAdd(out, 20.0f * (sRed[0] + sRed[1] + sRed[2] + sRed[3] + 16.0f * mb2v));
    }
    __syncthreads();
  }
#undef AFRAG
}

extern "C" void kernel_launch(void* const* d_in, const int* in_sizes, int n_in,
                              void* d_out, int out_size, void* d_ws, size_t ws_size,
                              hipStream_t stream) {
  const float* dR    = (const float*)d_in[0];
  const int*   Z     = (const int*)  d_in[1];
  const int*   nbr   = (const int*)  d_in[2];
  const float* embed = (const float*)d_in[3];
  const float* fw1   = (const float*)d_in[4];
  const float* fb1   = (const float*)d_in[5];
  const float* fw2   = (const float*)d_in[6];
  const float* fb2   = (const float*)d_in[7];
  const float* in2f  = (const float*)d_in[8];
  const float* w1    = (const float*)d_in[9];
  const float* b1    = (const float*)d_in[10];
  const float* w2    = (const float*)d_in[11];
  const float* b2    = (const float*)d_in[12];
  const float* mw1   = (const float*)d_in[13];
  const float* mb1   = (const float*)d_in[14];
  const float* mw2   = (const float*)d_in[15];
  const float* mb2   = (const float*)d_in[16];
  float* out = (float*)d_out;

  char* ws = (char*)d_ws;
  f16* tabh  = (f16*)ws;                                   // 98.6 KB (385 rows)
  f16* ytab  = (f16*)(ws + (size_t)128 * 1024);            // 25.6 KB
  f16* w1ht  = (f16*)(ws + (size_t)192 * 1024);            // 32 KB
  f16* w2ht  = (f16*)(ws + (size_t)256 * 1024);            // 32 KB
  f16* mw1ht = (f16*)(ws + (size_t)320 * 1024);            // 16 KB

  prep_all_kernel<<<NTB + 64, 256, 0, stream>>>(fw1, fb1, fw2, fb2,
      w1, w2, mw1, embed, in2f, tabh, ytab, w1ht, w2ht, mw1ht, out);
  schnet_main_kernel<<<PBLOCKS, 512, 0, stream>>>(dR, Z, nbr, embed,
      tabh, ytab, w1ht, b1, w2ht, b2, mw1ht, mb1, mw2, mb2, out);
}